// Round 5
// baseline (241.634 us; speedup 1.0000x reference)
//
#include <hip/hip_runtime.h>

#define DIM 1024
#define HEADS 16
#define HDIM 64
#define SEQ 2048
#define SCALEF 0.125f
// 0.125 * log2(e)
#define SCLOG2 0.18033688011112042f

typedef __attribute__((ext_vector_type(8))) short short8;
typedef __attribute__((ext_vector_type(4))) float f32x4;
typedef __attribute__((ext_vector_type(16))) float f32x16;
typedef __attribute__((ext_vector_type(4))) int i32x4;

static __device__ __forceinline__ unsigned short f2bf(float f){
  union { float f; unsigned int u; } v; v.f = f;
  unsigned int r = v.u + 0x7fffu + ((v.u >> 16) & 1u);
  return (unsigned short)(r >> 16);
}

static __device__ __forceinline__ int cvtpk(float lo, float hi){
  int r;
  asm("v_cvt_pk_bf16_f32 %0, %1, %2" : "=v"(r) : "v"(lo), "v"(hi));
  return r;
}
// after: a' = {a.lo32, b.lo32-of-other-half}: a'[l<32]=a[l], a'[l>=32]=b[l-32];
//        b'[l<32]=a[l+32], b'[l>=32]=b[l]
static __device__ __forceinline__ void swap32(int& a, int& b){
  asm("v_permlane32_swap_b32 %0, %1" : "+v"(a), "+v"(b));
}

__global__ void cast_kernel(const float* __restrict__ in, unsigned short* __restrict__ out, int n4){
  int i = blockIdx.x*blockDim.x + threadIdx.x;
  if (i < n4){
    float4 v = ((const float4*)in)[i];
    ushort4 o;
    o.x = f2bf(v.x); o.y = f2bf(v.y); o.z = f2bf(v.z); o.w = f2bf(v.w);
    ((ushort4*)out)[i] = o;
  }
}

// ---------------- GEMM: [4096,1024] x [Ncols,1024]^T -> head-scattered bf16 ----------------
#define BK 64
#define LDK (BK+8)

__global__ __launch_bounds__(256)
void gemm_proj(const unsigned short* __restrict__ Abuf,
               const unsigned short* __restrict__ Bbuf,
               unsigned short* __restrict__ dst0,
               unsigned short* __restrict__ dst1,
               int mode)
{
  __shared__ unsigned short Ald[128*LDK];
  __shared__ unsigned short Bld[128*LDK];
  const int tid  = threadIdx.x;
  const int lane = tid & 63;
  const int wid  = tid >> 6;
  const int wm = wid >> 1, wn = wid & 1;
  const int mbase = blockIdx.y * 128;
  const int nbase = blockIdx.x * 128;
  const int K = 1024;

  f32x4 acc[4][4];
  for (int i=0;i<4;i++) for(int j=0;j<4;j++) acc[i][j] = (f32x4){0.f,0.f,0.f,0.f};

  for (int kt = 0; kt < K; kt += BK){
    __syncthreads();
    #pragma unroll
    for (int it = 0; it < 4; ++it){
      int cid = tid + 256*it;
      int row = cid >> 3, c8 = cid & 7;
      short8 av = *(const short8*)(Abuf + (size_t)(mbase+row)*K + kt + c8*8);
      *(short8*)(Ald + row*LDK + c8*8) = av;
      short8 bv = *(const short8*)(Bbuf + (size_t)(nbase+row)*K + kt + c8*8);
      *(short8*)(Bld + row*LDK + c8*8) = bv;
    }
    __syncthreads();
    #pragma unroll
    for (int kc = 0; kc < 2; ++kc){
      short8 af[4], bf[4];
      #pragma unroll
      for (int mt=0; mt<4; ++mt)
        af[mt] = *(const short8*)(Ald + (wm*64 + mt*16 + (lane&15))*LDK + kc*32 + (lane>>4)*8);
      #pragma unroll
      for (int nt=0; nt<4; ++nt)
        bf[nt] = *(const short8*)(Bld + (wn*64 + nt*16 + (lane&15))*LDK + kc*32 + (lane>>4)*8);
      #pragma unroll
      for (int mt=0; mt<4; ++mt)
        #pragma unroll
        for (int nt=0; nt<4; ++nt)
          acc[mt][nt] = __builtin_amdgcn_mfma_f32_16x16x32_bf16(af[mt], bf[nt], acc[mt][nt], 0,0,0);
    }
  }

  #pragma unroll
  for (int mt=0; mt<4; ++mt){
    int mrow = mbase + wm*64 + mt*16 + (lane>>4)*4;
    #pragma unroll
    for (int nt=0; nt<4; ++nt){
      int col = nbase + wn*64 + nt*16 + (lane&15);
      #pragma unroll
      for (int r=0; r<4; ++r){
        int m = mrow + r;
        int b = m >> 11, n = m & 2047;
        unsigned short bv = f2bf(acc[mt][nt][r]);
        if (mode == 0){
          int h = col >> 6, d = col & 63;
          dst0[((size_t)((b*HEADS + h)*SEQ + n))*HDIM + d] = bv;
        } else {
          int t = col >> 10, c2 = col & 1023;
          int h = c2 >> 6, d = c2 & 63;
          unsigned short* dd = t ? dst1 : dst0;
          dd[((size_t)((b*HEADS + h)*SEQ + n))*HDIM + d] = bv;
        }
      }
    }
  }
}

// ---------------- transpose [bh][n][64] -> [bh][64][n] (plain) ----------------
__global__ __launch_bounds__(256)
void transpose_nd(const unsigned short* __restrict__ in, unsigned short* __restrict__ out){
  __shared__ unsigned short t[64*68];
  const int tid = threadIdx.x;
  const int bh = blockIdx.y;
  const int n0 = blockIdx.x * 64;
  const size_t base = (size_t)bh * SEQ * HDIM;
  #pragma unroll
  for (int it=0; it<2; ++it){
    int cid = tid + 256*it;
    int row = cid >> 3, c8 = cid & 7;
    *(short8*)(t + row*68 + c8*8) = *(const short8*)(in + base + (size_t)(n0+row)*HDIM + c8*8);
  }
  __syncthreads();
  #pragma unroll
  for (int it=0; it<2; ++it){
    int cid = tid + 256*it;
    int d = cid >> 3, c8 = cid & 7;
    short8 v;
    #pragma unroll
    for (int j=0;j<8;++j)
      ((short*)&v)[j] = t[(c8*8+j)*68 + d];
    *(short8*)(out + base + (size_t)d*SEQ + n0 + c8*8) = v;
  }
}

// ---------------- fused flash attention, swapped-operand 32x32, P in registers ----------
// Q row-major [bh][q][d]; K row-major [bh][key][d]; V pre-transposed [bh][d][key]
// mode 0: writes Y^T [bh][d][q] bf16. mode 1: writes fp32 out[b][q][h*64+d].
#define KT2 64
#define NT (SEQ/KT2)

__device__ __forceinline__ void gl_lds16(const unsigned short* g, unsigned short* l){
  __builtin_amdgcn_global_load_lds((const __attribute__((address_space(1))) void*)g,
                                   (__attribute__((address_space(3))) void*)l, 16, 0, 0);
}

__global__ __launch_bounds__(128)
void attn_pass(const unsigned short* __restrict__ Qb,
               const unsigned short* __restrict__ Kb,
               const unsigned short* __restrict__ Vtb,
               unsigned short* __restrict__ ytb,
               float* __restrict__ outf,
               int mode)
{
  // [buf][ K frags 8*512 | V frags 8*512 ] shorts
  __shared__ unsigned short SH[2][8192];
  const int tid = threadIdx.x, lane = tid & 63, wid = tid >> 6;  // 2 waves
  const int l31 = lane & 31, l5 = lane >> 5;

  // XCD-aware decode: 4 bh per XCD, all 32 q-blocks of a bh on one XCD
  const int bid = blockIdx.x;
  const int cx = bid & 7, j = bid >> 3;
  const int bh = cx*4 + (j >> 5);
  const int qb = j & 31;
  const int q0 = qb*64 + wid*32;               // this wave's 32 q-rows
  const size_t base = (size_t)bh * SEQ * HDIM;

  // Q^T B-fragments (col q = l31, k-rows d = db*16 + l5*8 ..+8), kept in regs
  short8 qf[4];
  #pragma unroll
  for (int db=0; db<4; ++db)
    qf[db] = *(const short8*)(Qb + base + (size_t)(q0 + l31)*HDIM + db*16 + l5*8);

  // staging: wave0 -> 8 K frags, wave1 -> 8 V frags (frag-ordered linear LDS)
  const unsigned short* gsrc[8];
  #pragma unroll
  for (int f=0; f<8; ++f){
    if (wid == 0){
      int kb = f >> 2, db = f & 3;   // K frag: key = kb*32 + l31, d = db*16 + l5*8
      gsrc[f] = Kb + base + (size_t)(kb*32 + l31)*HDIM + db*16 + l5*8;
    } else {
      int db2 = f >> 2, kb2 = f & 3; // V frag: d = db2*32 + l31, key = kb2*16 + l5*8
      gsrc[f] = Vtb + base + (size_t)(db2*32 + l31)*SEQ + kb2*16 + l5*8;
    }
  }
  const int sstep = (wid == 0) ? KT2*HDIM : KT2;
  const int ldsoff = wid ? 4096 : 0;

  f32x16 oo0, oo1;
  #pragma unroll
  for (int r=0;r<16;++r){ oo0[r]=0.f; oo1[r]=0.f; }
  float osum = 0.f;

  #pragma unroll
  for (int f=0; f<8; ++f)
    gl_lds16(gsrc[f], &SH[0][ldsoff + f*512]);
  __syncthreads();

  for (int t = 0; t < NT; ++t){
    const int cur = t & 1;
    if (t+1 < NT){
      #pragma unroll
      for (int f=0; f<8; ++f)
        gl_lds16(gsrc[f] + (size_t)(t+1)*sstep, &SH[cur^1][ldsoff + f*512]);
    }
    const unsigned short* Kc = &SH[cur][0];
    const unsigned short* Vc = &SH[cur][4096];

    // S^T = K * Q^T : lane holds col q=q0+l31, rows key = kb*32 + (r&3)+8*(r>>2)+4*l5
    float p[32];
    #pragma unroll
    for (int kb=0; kb<2; ++kb){
      f32x16 sacc;
      #pragma unroll
      for (int r=0;r<16;++r) sacc[r]=0.f;
      #pragma unroll
      for (int db=0; db<4; ++db){
        short8 kfr = *(const short8*)(Kc + (kb*4+db)*512 + lane*8);
        sacc = __builtin_amdgcn_mfma_f32_32x32x16_bf16(kfr, qf[db], sacc, 0,0,0);
      }
      #pragma unroll
      for (int r=0;r<16;++r){
        float pv = exp2f(sacc[r]*SCLOG2);
        p[kb*16+r] = pv;
        osum += pv;
      }
    }

    // build P^T B-frags in registers (cvt_pk + permlane32_swap), feed PV
    #pragma unroll
    for (int kb2=0; kb2<4; ++kb2){
      const int pb = (kb2>>1)*16 + (kb2&1)*8;
      int a0 = cvtpk(p[pb+0], p[pb+1]);
      int b0 = cvtpk(p[pb+4], p[pb+5]);
      int a1 = cvtpk(p[pb+2], p[pb+3]);
      int b1 = cvtpk(p[pb+6], p[pb+7]);
      swap32(a0, b0);
      swap32(a1, b1);
      i32x4 pav; pav[0]=a0; pav[1]=a1; pav[2]=b0; pav[3]=b1;
      short8 paf = *(short8*)&pav;
      short8 v0 = *(const short8*)(Vc + (0*4+kb2)*512 + lane*8);
      oo0 = __builtin_amdgcn_mfma_f32_32x32x16_bf16(v0, paf, oo0, 0,0,0);
      short8 v1 = *(const short8*)(Vc + (1*4+kb2)*512 + lane*8);
      oo1 = __builtin_amdgcn_mfma_f32_32x32x16_bf16(v1, paf, oo1, 0,0,0);
    }
    __syncthreads();
  }

  // finalize: lane l and l^32 hold complementary keys of the same q
  osum += __shfl_xor(osum, 32);
  const float rinv = 1.0f / osum;

  if (mode == 0){
    // O^T: row d = db2*32 + (r&3)+8*(r>>2)+4*l5, col q = q0+l31 -> Y^T[bh][d][q]
    #pragma unroll
    for (int r=0;r<16;++r){
      int d0 = (r&3) + 8*(r>>2) + 4*l5;
      ytb[base + (size_t)(d0)*SEQ + q0 + l31]      = f2bf(oo0[r]*rinv);
      ytb[base + (size_t)(d0+32)*SEQ + q0 + l31]   = f2bf(oo1[r]*rinv);
    }
  } else {
    // bounce through LDS for coalesced fp32 stores
    __syncthreads();
    float* Of = (float*)&SH[0][0];   // 64 q x 68 pad floats = 17.4 KB
    const int ql = wid*32 + l31;
    #pragma unroll
    for (int r=0;r<16;++r){
      int d0 = (r&3) + 8*(r>>2) + 4*l5;
      Of[ql*68 + d0]      = oo0[r]*rinv;
      Of[ql*68 + d0 + 32] = oo1[r]*rinv;
    }
    __syncthreads();
    const int b = bh >> 4, h = bh & 15;
    const int qr = tid >> 1, dh = (tid & 1)*32;
    const float* src = Of + qr*68 + dh;
    float* drow = outf + ((size_t)(b*SEQ + qb*64 + qr))*DIM + h*HDIM + dh;
    #pragma unroll
    for (int k2=0;k2<8;++k2)
      *(float4*)(drow + k2*4) = *(const float4*)(src + k2*4);
  }
}

extern "C" void kernel_launch(void* const* d_in, const int* in_sizes, int n_in,
                              void* d_out, int out_size, void* d_ws, size_t ws_size,
                              hipStream_t stream) {
  const float* x   = (const float*)d_in[0];
  const float* x2  = (const float*)d_in[1];
  const float* Wq  = (const float*)d_in[2];
  const float* Wa  = (const float*)d_in[3];
  const float* Wkv = (const float*)d_in[4];
  float* out = (float*)d_out;

  unsigned short* ws = (unsigned short*)d_ws;
  unsigned short* xb   = ws;                      // 4096*1024
  unsigned short* x2b  = xb   + 4096*1024;
  unsigned short* Wqb  = x2b  + 4096*1024;        // 1024*1024
  unsigned short* Wab  = Wqb  + 1024*1024;
  unsigned short* Wkvb = Wab  + 1024*1024;        // 2048*1024
  unsigned short* Qw   = Wkvb + 2048*1024;        // BHND = 4194304 each
  unsigned short* Aw   = Qw   + 4194304;
  unsigned short* Kw   = Aw   + 4194304;
  unsigned short* Vw   = Kw   + 4194304;
  unsigned short* Vwt  = Vw   + 4194304;          // V^T [bh][d][n]
  unsigned short* Ywt  = xb;                      // Y^T [bh][d][n] (xb dead after gemms)

  cast_kernel<<<dim3(4096), dim3(256), 0, stream>>>(x,   xb,   4096*1024/4);
  cast_kernel<<<dim3(4096), dim3(256), 0, stream>>>(x2,  x2b,  4096*1024/4);
  cast_kernel<<<dim3(1024), dim3(256), 0, stream>>>(Wq,  Wqb,  1024*1024/4);
  cast_kernel<<<dim3(1024), dim3(256), 0, stream>>>(Wa,  Wab,  1024*1024/4);
  cast_kernel<<<dim3(2048), dim3(256), 0, stream>>>(Wkv, Wkvb, 2048*1024/4);

  gemm_proj<<<dim3(8, 32),  dim3(256), 0, stream>>>(xb,  Wqb,  Qw, nullptr, 0);
  gemm_proj<<<dim3(8, 32),  dim3(256), 0, stream>>>(x2b, Wab,  Aw, nullptr, 0);
  gemm_proj<<<dim3(16, 32), dim3(256), 0, stream>>>(xb,  Wkvb, Kw, Vw,      1);

  transpose_nd<<<dim3(32, 32), dim3(256), 0, stream>>>(Vw, Vwt);

  // pass 1: Y^T = (softmax(A k^T s) v)^T  -- written directly transposed
  attn_pass<<<dim3(1024), dim3(128), 0, stream>>>(Aw, Kw, Vwt, Ywt, nullptr, 0);

  // pass 2: out = softmax(q A^T s) Y
  attn_pass<<<dim3(1024), dim3(128), 0, stream>>>(Qw, Aw, Ywt, nullptr, out, 1);
}

// Round 6
// 219.145 us; speedup vs baseline: 1.1026x; 1.1026x over previous
//
#include <hip/hip_runtime.h>

#define DIM 1024
#define HEADS 16
#define HDIM 64
#define SEQ 2048
// 0.125 * log2(e) — folded into A's projection epilogue
#define SCLOG2 0.18033688011112042f

typedef __attribute__((ext_vector_type(8))) short short8;
typedef __attribute__((ext_vector_type(4))) float f32x4;
typedef __attribute__((ext_vector_type(16))) float f32x16;
typedef __attribute__((ext_vector_type(4))) int i32x4;

static __device__ __forceinline__ unsigned short f2bf(float f){
  union { float f; unsigned int u; } v; v.f = f;
  unsigned int r = v.u + 0x7fffu + ((v.u >> 16) & 1u);
  return (unsigned short)(r >> 16);
}

static __device__ __forceinline__ int cvtpk(float lo, float hi){
  int r;
  asm("v_cvt_pk_bf16_f32 %0, %1, %2" : "=v"(r) : "v"(lo), "v"(hi));
  return r;
}
static __device__ __forceinline__ void swap32(int& a, int& b){
  asm("v_permlane32_swap_b32 %0, %1" : "+v"(a), "+v"(b));
}

__global__ void cast_kernel(const float* __restrict__ in, unsigned short* __restrict__ out, int n4){
  int i = blockIdx.x*blockDim.x + threadIdx.x;
  if (i < n4){
    float4 v = ((const float4*)in)[i];
    ushort4 o;
    o.x = f2bf(v.x); o.y = f2bf(v.y); o.z = f2bf(v.z); o.w = f2bf(v.w);
    ((ushort4*)out)[i] = o;
  }
}

// ---------------- GEMM: [4096,1024] x [Ncols,1024]^T -> head-scattered bf16 ----------------
#define BK 64
#define LDK (BK+8)

__global__ __launch_bounds__(256)
void gemm_proj(const unsigned short* __restrict__ Abuf,
               const unsigned short* __restrict__ Bbuf,
               unsigned short* __restrict__ dst0,
               unsigned short* __restrict__ dst1,
               int mode, float scale)
{
  __shared__ unsigned short Ald[128*LDK];
  __shared__ unsigned short Bld[128*LDK];
  const int tid  = threadIdx.x;
  const int lane = tid & 63;
  const int wid  = tid >> 6;
  const int wm = wid >> 1, wn = wid & 1;
  const int mbase = blockIdx.y * 128;
  const int nbase = blockIdx.x * 128;
  const int K = 1024;

  f32x4 acc[4][4];
  for (int i=0;i<4;i++) for(int j=0;j<4;j++) acc[i][j] = (f32x4){0.f,0.f,0.f,0.f};

  for (int kt = 0; kt < K; kt += BK){
    __syncthreads();
    #pragma unroll
    for (int it = 0; it < 4; ++it){
      int cid = tid + 256*it;
      int row = cid >> 3, c8 = cid & 7;
      short8 av = *(const short8*)(Abuf + (size_t)(mbase+row)*K + kt + c8*8);
      *(short8*)(Ald + row*LDK + c8*8) = av;
      short8 bv = *(const short8*)(Bbuf + (size_t)(nbase+row)*K + kt + c8*8);
      *(short8*)(Bld + row*LDK + c8*8) = bv;
    }
    __syncthreads();
    #pragma unroll
    for (int kc = 0; kc < 2; ++kc){
      short8 af[4], bf[4];
      #pragma unroll
      for (int mt=0; mt<4; ++mt)
        af[mt] = *(const short8*)(Ald + (wm*64 + mt*16 + (lane&15))*LDK + kc*32 + (lane>>4)*8);
      #pragma unroll
      for (int nt=0; nt<4; ++nt)
        bf[nt] = *(const short8*)(Bld + (wn*64 + nt*16 + (lane&15))*LDK + kc*32 + (lane>>4)*8);
      #pragma unroll
      for (int mt=0; mt<4; ++mt)
        #pragma unroll
        for (int nt=0; nt<4; ++nt)
          acc[mt][nt] = __builtin_amdgcn_mfma_f32_16x16x32_bf16(af[mt], bf[nt], acc[mt][nt], 0,0,0);
    }
  }

  #pragma unroll
  for (int mt=0; mt<4; ++mt){
    int mrow = mbase + wm*64 + mt*16 + (lane>>4)*4;
    #pragma unroll
    for (int nt=0; nt<4; ++nt){
      int col = nbase + wn*64 + nt*16 + (lane&15);
      #pragma unroll
      for (int r=0; r<4; ++r){
        int m = mrow + r;
        int b = m >> 11, n = m & 2047;
        unsigned short bv = f2bf(acc[mt][nt][r] * scale);
        if (mode == 0){
          int h = col >> 6, d = col & 63;
          dst0[((size_t)((b*HEADS + h)*SEQ + n))*HDIM + d] = bv;
        } else {
          int t = col >> 10, c2 = col & 1023;
          int h = c2 >> 6, d = c2 & 63;
          unsigned short* dd = t ? dst1 : dst0;
          dd[((size_t)((b*HEADS + h)*SEQ + n))*HDIM + d] = bv;
        }
      }
    }
  }
}

// ---------------- transpose [bh][n][64] -> [bh][64][n] ----------------
__global__ __launch_bounds__(256)
void transpose_nd(const unsigned short* __restrict__ in, unsigned short* __restrict__ out){
  __shared__ unsigned short t[64*68];
  const int tid = threadIdx.x;
  const int bh = blockIdx.y;
  const int n0 = blockIdx.x * 64;
  const size_t base = (size_t)bh * SEQ * HDIM;
  #pragma unroll
  for (int it=0; it<2; ++it){
    int cid = tid + 256*it;
    int row = cid >> 3, c8 = cid & 7;
    *(short8*)(t + row*68 + c8*8) = *(const short8*)(in + base + (size_t)(n0+row)*HDIM + c8*8);
  }
  __syncthreads();
  #pragma unroll
  for (int it=0; it<2; ++it){
    int cid = tid + 256*it;
    int d = cid >> 3, c8 = cid & 7;
    short8 v;
    #pragma unroll
    for (int j=0;j<8;++j)
      ((short*)&v)[j] = t[(c8*8+j)*68 + d];
    *(short8*)(out + base + (size_t)d*SEQ + n0 + c8*8) = v;
  }
}

// ---------------- fused flash attention, swapped-operand 32x32, P in registers ----------
// Q row-major [bh][q][d]; K row-major [bh][key][d]; V pre-transposed [bh][d][key]
// mode 0: writes Y^T [bh][d][q] bf16. mode 1: writes fp32 out[b][q][h*64+d].
// 4 waves/block, 32 q-rows per wave (128 q/block), grid 512, 4 blocks/CU.
#define KT2 64
#define NT (SEQ/KT2)

__device__ __forceinline__ void gl_lds16(const unsigned short* g, unsigned short* l){
  __builtin_amdgcn_global_load_lds((const __attribute__((address_space(1))) void*)g,
                                   (__attribute__((address_space(3))) void*)l, 16, 0, 0);
}

__global__ __launch_bounds__(256)
void attn_pass(const unsigned short* __restrict__ Qb,
               const unsigned short* __restrict__ Kb,
               const unsigned short* __restrict__ Vtb,
               unsigned short* __restrict__ ytb,
               float* __restrict__ outf,
               int mode)
{
  // union: [2][16 frags * 512 shorts] staging  |  [128][68] float out-bounce
  __shared__ __align__(16) char SHRAW[34816];
  unsigned short* SH0 = (unsigned short*)SHRAW;
  unsigned short* SH1 = SH0 + 8192;
  const int tid = threadIdx.x, lane = tid & 63, wid = tid >> 6;  // 4 waves
  const int l31 = lane & 31, l5 = lane >> 5;

  // XCD-aware decode: 4 bh per XCD, all 16 q-blocks of a bh on one XCD
  const int bid = blockIdx.x;
  const int cx = bid & 7, j = bid >> 3;
  const int bh = cx*4 + (j >> 4);
  const int qb = j & 15;
  const int q0 = qb*128 + wid*32;               // this wave's 32 q-rows
  const size_t base = (size_t)bh * SEQ * HDIM;

  // Q^T B-fragments (col q = l31, k-rows d = db*16 + l5*8 ..+8)
  short8 qf[4];
  #pragma unroll
  for (int db=0; db<4; ++db)
    qf[db] = *(const short8*)(Qb + base + (size_t)(q0 + l31)*HDIM + db*16 + l5*8);

  // staging: waves 0,1 -> K frags (kb=wid), waves 2,3 -> V frags (db2=wid-2)
  const unsigned short* gsrc[4];
  int ldst[4];
  int sstep;
  if (wid < 2){
    #pragma unroll
    for (int f=0; f<4; ++f){
      gsrc[f] = Kb + base + (size_t)(wid*32 + l31)*HDIM + f*16 + l5*8;
      ldst[f] = (wid*4 + f)*512;
    }
    sstep = KT2*HDIM;
  } else {
    const int db2 = wid - 2;
    #pragma unroll
    for (int f=0; f<4; ++f){
      gsrc[f] = Vtb + base + (size_t)(db2*32 + l31)*SEQ + f*16 + l5*8;
      ldst[f] = 4096 + (db2*4 + f)*512;
    }
    sstep = KT2;
  }

  f32x16 oo0, oo1;
  #pragma unroll
  for (int r=0;r<16;++r){ oo0[r]=0.f; oo1[r]=0.f; }
  float os[4] = {0.f,0.f,0.f,0.f};

  #pragma unroll
  for (int f=0; f<4; ++f)
    gl_lds16(gsrc[f], SH0 + ldst[f]);
  __syncthreads();

  for (int t = 0; t < NT; ++t){
    unsigned short* Sc = (t & 1) ? SH1 : SH0;
    unsigned short* Sd = (t & 1) ? SH0 : SH1;
    if (t+1 < NT){
      #pragma unroll
      for (int f=0; f<4; ++f)
        gl_lds16(gsrc[f] + (size_t)(t+1)*sstep, Sd + ldst[f]);
    }
    const unsigned short* Kc = Sc;
    const unsigned short* Vc = Sc + 4096;

    // S^T = K * Q^T : lane = col q0+l31, rows key = kb*32 + (r&3)+8*(r>>2)+4*l5
    float p[32];
    #pragma unroll
    for (int kb=0; kb<2; ++kb){
      f32x16 sacc;
      #pragma unroll
      for (int r=0;r<16;++r) sacc[r]=0.f;
      #pragma unroll
      for (int db=0; db<4; ++db){
        short8 kfr = *(const short8*)(Kc + (kb*4+db)*512 + lane*8);
        sacc = __builtin_amdgcn_mfma_f32_32x32x16_bf16(kfr, qf[db], sacc, 0,0,0);
      }
      #pragma unroll
      for (int r=0;r<16;++r){
        float pv = exp2f(sacc[r]);       // scale pre-folded into A projection
        p[kb*16+r] = pv;
        os[r & 3] += pv;                 // 4 independent partial-sum chains
      }
    }

    // build P^T B-frags in registers, feed PV
    #pragma unroll
    for (int kb2=0; kb2<4; ++kb2){
      const int pb = (kb2>>1)*16 + (kb2&1)*8;
      int a0 = cvtpk(p[pb+0], p[pb+1]);
      int b0 = cvtpk(p[pb+4], p[pb+5]);
      int a1 = cvtpk(p[pb+2], p[pb+3]);
      int b1 = cvtpk(p[pb+6], p[pb+7]);
      swap32(a0, b0);
      swap32(a1, b1);
      i32x4 pav; pav[0]=a0; pav[1]=a1; pav[2]=b0; pav[3]=b1;
      short8 paf = *(short8*)&pav;
      short8 v0 = *(const short8*)(Vc + (0*4+kb2)*512 + lane*8);
      oo0 = __builtin_amdgcn_mfma_f32_32x32x16_bf16(v0, paf, oo0, 0,0,0);
      short8 v1 = *(const short8*)(Vc + (1*4+kb2)*512 + lane*8);
      oo1 = __builtin_amdgcn_mfma_f32_32x32x16_bf16(v1, paf, oo1, 0,0,0);
    }
    __syncthreads();
  }

  float osum = (os[0]+os[1]) + (os[2]+os[3]);
  osum += __shfl_xor(osum, 32);
  const float rinv = 1.0f / osum;

  if (mode == 0){
    #pragma unroll
    for (int r=0;r<16;++r){
      int d0 = (r&3) + 8*(r>>2) + 4*l5;
      ytb[base + (size_t)(d0)*SEQ + q0 + l31]      = f2bf(oo0[r]*rinv);
      ytb[base + (size_t)(d0+32)*SEQ + q0 + l31]   = f2bf(oo1[r]*rinv);
    }
  } else {
    __syncthreads();
    float* Of = (float*)SHRAW;    // [128][68]
    const int ql = wid*32 + l31;
    #pragma unroll
    for (int r=0;r<16;++r){
      int d0 = (r&3) + 8*(r>>2) + 4*l5;
      Of[ql*68 + d0]      = oo0[r]*rinv;
      Of[ql*68 + d0 + 32] = oo1[r]*rinv;
    }
    __syncthreads();
    const int b = bh >> 4, h = bh & 15;
    const int qr = tid >> 1, dh = (tid & 1)*32;
    const float* src = Of + qr*68 + dh;
    float* drow = outf + ((size_t)(b*SEQ + qb*128 + qr))*DIM + h*HDIM + dh;
    #pragma unroll
    for (int k2=0;k2<8;++k2)
      *(float4*)(drow + k2*4) = *(const float4*)(src + k2*4);
  }
}

extern "C" void kernel_launch(void* const* d_in, const int* in_sizes, int n_in,
                              void* d_out, int out_size, void* d_ws, size_t ws_size,
                              hipStream_t stream) {
  const float* x   = (const float*)d_in[0];
  const float* x2  = (const float*)d_in[1];
  const float* Wq  = (const float*)d_in[2];
  const float* Wa  = (const float*)d_in[3];
  const float* Wkv = (const float*)d_in[4];
  float* out = (float*)d_out;

  unsigned short* ws = (unsigned short*)d_ws;
  unsigned short* xb   = ws;                      // 4096*1024
  unsigned short* x2b  = xb   + 4096*1024;
  unsigned short* Wqb  = x2b  + 4096*1024;        // 1024*1024
  unsigned short* Wab  = Wqb  + 1024*1024;
  unsigned short* Wkvb = Wab  + 1024*1024;        // 2048*1024
  unsigned short* Qw   = Wkvb + 2048*1024;        // BHND = 4194304 each
  unsigned short* Aw   = Qw   + 4194304;
  unsigned short* Kw   = Aw   + 4194304;
  unsigned short* Vw   = Kw   + 4194304;
  unsigned short* Vwt  = Vw   + 4194304;          // V^T [bh][d][n]
  unsigned short* Ywt  = xb;                      // Y^T [bh][d][n] (xb dead after gemms)

  cast_kernel<<<dim3(4096), dim3(256), 0, stream>>>(x,   xb,   4096*1024/4);
  cast_kernel<<<dim3(4096), dim3(256), 0, stream>>>(x2,  x2b,  4096*1024/4);
  cast_kernel<<<dim3(1024), dim3(256), 0, stream>>>(Wq,  Wqb,  1024*1024/4);
  cast_kernel<<<dim3(1024), dim3(256), 0, stream>>>(Wa,  Wab,  1024*1024/4);
  cast_kernel<<<dim3(2048), dim3(256), 0, stream>>>(Wkv, Wkvb, 2048*1024/4);

  gemm_proj<<<dim3(8, 32),  dim3(256), 0, stream>>>(xb,  Wqb,  Qw, nullptr, 0, 1.0f);
  // A pre-scaled by 0.125*log2(e): query of pass 1 AND key of pass 2
  gemm_proj<<<dim3(8, 32),  dim3(256), 0, stream>>>(x2b, Wab,  Aw, nullptr, 0, SCLOG2);
  gemm_proj<<<dim3(16, 32), dim3(256), 0, stream>>>(xb,  Wkvb, Kw, Vw,      1, 1.0f);

  transpose_nd<<<dim3(32, 32), dim3(256), 0, stream>>>(Vw, Vwt);

  // pass 1: Y^T = (softmax(A k^T s) v)^T  -- written directly transposed
  attn_pass<<<dim3(512), dim3(256), 0, stream>>>(Aw, Kw, Vwt, Ywt, nullptr, 0);

  // pass 2: out = softmax(q A^T s) Y
  attn_pass<<<dim3(512), dim3(256), 0, stream>>>(Qw, Aw, Ywt, nullptr, out, 1);
}

// Round 7
// 201.327 us; speedup vs baseline: 1.2002x; 1.0885x over previous
//
#include <hip/hip_runtime.h>

#define DIM 1024
#define HEADS 16
#define HDIM 64
#define SEQ 2048
// 0.125 * log2(e) — folded into A's projection epilogue
#define SCLOG2 0.18033688011112042f

typedef __attribute__((ext_vector_type(8))) short short8;
typedef __attribute__((ext_vector_type(4))) float f32x4;
typedef __attribute__((ext_vector_type(16))) float f32x16;
typedef __attribute__((ext_vector_type(4))) int i32x4;

static __device__ __forceinline__ unsigned short f2bf(float f){
  union { float f; unsigned int u; } v; v.f = f;
  unsigned int r = v.u + 0x7fffu + ((v.u >> 16) & 1u);
  return (unsigned short)(r >> 16);
}

static __device__ __forceinline__ int cvtpk(float lo, float hi){
  int r;
  asm("v_cvt_pk_bf16_f32 %0, %1, %2" : "=v"(r) : "v"(lo), "v"(hi));
  return r;
}
static __device__ __forceinline__ void swap32(int& a, int& b){
  asm("v_permlane32_swap_b32 %0, %1" : "+v"(a), "+v"(b));
}

__global__ void cast_kernel(const float* __restrict__ in, unsigned short* __restrict__ out, int n4){
  int i = blockIdx.x*blockDim.x + threadIdx.x;
  if (i < n4){
    float4 v = ((const float4*)in)[i];
    ushort4 o;
    o.x = f2bf(v.x); o.y = f2bf(v.y); o.z = f2bf(v.z); o.w = f2bf(v.w);
    ((ushort4*)out)[i] = o;
  }
}

// ---------------- GEMM: [4096,1024] x [Ncols,1024]^T -> head-scattered bf16 ----------------
// mode 0: dst0[bh][n][d]. mode 1: K -> dst0[bh][n][d], V -> dst1[bh][d][n] (transposed!)
#define BK 64
#define LDK (BK+8)

__global__ __launch_bounds__(256)
void gemm_proj(const unsigned short* __restrict__ Abuf,
               const unsigned short* __restrict__ Bbuf,
               unsigned short* __restrict__ dst0,
               unsigned short* __restrict__ dst1,
               int mode, float scale)
{
  __shared__ unsigned short Ald[128*LDK];
  __shared__ unsigned short Bld[128*LDK];
  const int tid  = threadIdx.x;
  const int lane = tid & 63;
  const int wid  = tid >> 6;
  const int wm = wid >> 1, wn = wid & 1;
  const int mbase = blockIdx.y * 128;
  const int nbase = blockIdx.x * 128;
  const int K = 1024;

  f32x4 acc[4][4];
  for (int i=0;i<4;i++) for(int j=0;j<4;j++) acc[i][j] = (f32x4){0.f,0.f,0.f,0.f};

  for (int kt = 0; kt < K; kt += BK){
    __syncthreads();
    #pragma unroll
    for (int it = 0; it < 4; ++it){
      int cid = tid + 256*it;
      int row = cid >> 3, c8 = cid & 7;
      short8 av = *(const short8*)(Abuf + (size_t)(mbase+row)*K + kt + c8*8);
      *(short8*)(Ald + row*LDK + c8*8) = av;
      short8 bv = *(const short8*)(Bbuf + (size_t)(nbase+row)*K + kt + c8*8);
      *(short8*)(Bld + row*LDK + c8*8) = bv;
    }
    __syncthreads();
    #pragma unroll
    for (int kc = 0; kc < 2; ++kc){
      short8 af[4], bf[4];
      #pragma unroll
      for (int mt=0; mt<4; ++mt)
        af[mt] = *(const short8*)(Ald + (wm*64 + mt*16 + (lane&15))*LDK + kc*32 + (lane>>4)*8);
      #pragma unroll
      for (int nt=0; nt<4; ++nt)
        bf[nt] = *(const short8*)(Bld + (wn*64 + nt*16 + (lane&15))*LDK + kc*32 + (lane>>4)*8);
      #pragma unroll
      for (int mt=0; mt<4; ++mt)
        #pragma unroll
        for (int nt=0; nt<4; ++nt)
          acc[mt][nt] = __builtin_amdgcn_mfma_f32_16x16x32_bf16(af[mt], bf[nt], acc[mt][nt], 0,0,0);
    }
  }

  #pragma unroll
  for (int mt=0; mt<4; ++mt){
    int mrow = mbase + wm*64 + mt*16 + (lane>>4)*4;   // multiple of 4
    int b = mrow >> 11, nblk = mrow & 2047;
    #pragma unroll
    for (int nt=0; nt<4; ++nt){
      int col = nbase + wn*64 + nt*16 + (lane&15);
      if (mode == 1 && (col >> 10)){
        // V -> V^T[bh][d][n], 4 consecutive n packed
        int c2 = col & 1023, h = c2 >> 6, d = c2 & 63;
        ushort4 pk;
        pk.x = f2bf(acc[mt][nt][0] * scale);
        pk.y = f2bf(acc[mt][nt][1] * scale);
        pk.z = f2bf(acc[mt][nt][2] * scale);
        pk.w = f2bf(acc[mt][nt][3] * scale);
        *(ushort4*)(dst1 + ((size_t)((b*HEADS + h)*HDIM + d))*SEQ + nblk) = pk;
      } else {
        int c2 = col & 1023, h = c2 >> 6, d = c2 & 63;
        #pragma unroll
        for (int r=0; r<4; ++r)
          dst0[((size_t)((b*HEADS + h)*SEQ + nblk + r))*HDIM + d] = f2bf(acc[mt][nt][r] * scale);
      }
    }
  }
}

// ---------------- fused flash attention, swapped-operand 32x32, in-block KV split ----------
// Q row-major [bh][q][d]; K row-major [bh][key][d]; V pre-transposed [bh][d][key]
// 8 waves: qw = wid&3 (32 q-rows each), kvh = wid>>2 (keys kvh*1024 .. +1024)
// mode 0: writes Y^T [bh][d][q] bf16. mode 1: writes fp32 out[b][q][h*64+d].
#define KT2 64
#define NTH 16     // tiles per kv half

__device__ __forceinline__ void gl_lds16(const unsigned short* g, unsigned short* l){
  __builtin_amdgcn_global_load_lds((const __attribute__((address_space(1))) void*)g,
                                   (__attribute__((address_space(3))) void*)l, 16, 0, 0);
}

__global__ __launch_bounds__(512)
void attn_pass(const unsigned short* __restrict__ Qb,
               const unsigned short* __restrict__ Kb,
               const unsigned short* __restrict__ Vtb,
               unsigned short* __restrict__ ytb,
               float* __restrict__ outf,
               int mode)
{
  // staging: [kvh][buf][16 frags * 512 shorts] = 64 KB; merge Of[128][68] f32 + Os overlay
  __shared__ __align__(16) char SHRAW[65536];
  unsigned short* SH = (unsigned short*)SHRAW;
  const int tid = threadIdx.x, lane = tid & 63, wid = tid >> 6;  // 8 waves
  const int l31 = lane & 31, l5 = lane >> 5;
  const int qw = wid & 3, kvh = wid >> 2;

  // XCD-aware decode: 4 bh per XCD, all 16 q-blocks of a bh on one XCD
  const int bid = blockIdx.x;
  const int cx = bid & 7, j = bid >> 3;
  const int bh = cx*4 + (j >> 4);
  const int qb = j & 15;
  const int q0 = qb*128 + qw*32;               // this wave's 32 q-rows
  const size_t base = (size_t)bh * SEQ * HDIM;

  // Q^T B-fragments (col q = l31, k-rows d = db*16 + l5*8 ..+8)
  short8 qf[4];
  #pragma unroll
  for (int db=0; db<4; ++db)
    qf[db] = *(const short8*)(Qb + base + (size_t)(q0 + l31)*HDIM + db*16 + l5*8);

  // staging duty within kv-group: qw 0,1 -> K frags, qw 2,3 -> V frags
  const unsigned short* gsrc[4];
  int ldst[4];
  int sstep;
  const int grpoff = kvh * 16384;
  if (qw < 2){
    #pragma unroll
    for (int f=0; f<4; ++f){
      gsrc[f] = Kb + base + (size_t)(kvh*1024 + qw*32 + l31)*HDIM + f*16 + l5*8;
      ldst[f] = grpoff + (qw*4 + f)*512;
    }
    sstep = KT2*HDIM;
  } else {
    const int db2 = qw - 2;
    #pragma unroll
    for (int f=0; f<4; ++f){
      gsrc[f] = Vtb + base + (size_t)(db2*32 + l31)*SEQ + kvh*1024 + f*16 + l5*8;
      ldst[f] = grpoff + 4096 + (db2*4 + f)*512;
    }
    sstep = KT2;
  }

  f32x16 oo0, oo1, ssum;
  #pragma unroll
  for (int r=0;r<16;++r){ oo0[r]=0.f; oo1[r]=0.f; ssum[r]=0.f; }
  short8 ones;
  #pragma unroll
  for (int jj=0;jj<8;++jj) ones[jj] = (short)0x3F80;

  #pragma unroll
  for (int f=0; f<4; ++f)
    gl_lds16(gsrc[f], SH + ldst[f]);
  __syncthreads();

  for (int t = 0; t < NTH; ++t){
    const int cur = t & 1;
    if (t+1 < NTH){
      const int pbuf = ((t+1) & 1) * 8192;
      #pragma unroll
      for (int f=0; f<4; ++f)
        gl_lds16(gsrc[f] + (size_t)(t+1)*sstep, SH + ldst[f] + pbuf);
    }
    const unsigned short* Kc = SH + grpoff + cur*8192;
    const unsigned short* Vc = Kc + 4096;

    // S^T = K * Q^T : lane = col q0+l31, rows key = kb*32 + (r&3)+8*(r>>2)+4*l5
    float p[32];
    #pragma unroll
    for (int kb=0; kb<2; ++kb){
      f32x16 sacc;
      #pragma unroll
      for (int r=0;r<16;++r) sacc[r]=0.f;
      #pragma unroll
      for (int db=0; db<4; ++db){
        short8 kfr = *(const short8*)(Kc + (kb*4+db)*512 + lane*8);
        sacc = __builtin_amdgcn_mfma_f32_32x32x16_bf16(kfr, qf[db], sacc, 0,0,0);
      }
      #pragma unroll
      for (int r=0;r<16;++r)
        p[kb*16+r] = exp2f(sacc[r]);     // scale pre-folded into A projection
    }

    // build P^T B-frags in registers; PV + ones-MFMA rowsum
    #pragma unroll
    for (int kb2=0; kb2<4; ++kb2){
      const int pb = (kb2>>1)*16 + (kb2&1)*8;
      int a0 = cvtpk(p[pb+0], p[pb+1]);
      int b0 = cvtpk(p[pb+4], p[pb+5]);
      int a1 = cvtpk(p[pb+2], p[pb+3]);
      int b1 = cvtpk(p[pb+6], p[pb+7]);
      swap32(a0, b0);
      swap32(a1, b1);
      i32x4 pav; pav[0]=a0; pav[1]=a1; pav[2]=b0; pav[3]=b1;
      short8 paf = *(short8*)&pav;
      ssum = __builtin_amdgcn_mfma_f32_32x32x16_bf16(ones, paf, ssum, 0,0,0);
      short8 v0 = *(const short8*)(Vc + (0*4+kb2)*512 + lane*8);
      oo0 = __builtin_amdgcn_mfma_f32_32x32x16_bf16(v0, paf, oo0, 0,0,0);
      short8 v1 = *(const short8*)(Vc + (1*4+kb2)*512 + lane*8);
      oo1 = __builtin_amdgcn_mfma_f32_32x32x16_bf16(v1, paf, oo1, 0,0,0);
    }
    __syncthreads();
  }

  // ---- in-block merge of the two kv halves ----
  float* Of  = (float*)SHRAW;                 // [128][68]
  float* Os1 = (float*)(SHRAW + 128*68*4);    // [128]
  const int ql = qw*32 + l31;

  if (kvh == 1){
    #pragma unroll
    for (int g=0; g<4; ++g){
      f32x4 w0, w1;
      #pragma unroll
      for (int r=0;r<4;++r){ w0[r] = oo0[g*4+r]; w1[r] = oo1[g*4+r]; }
      int d0 = 8*g + 4*l5;
      *(f32x4*)(Of + ql*68 + d0)      = w0;
      *(f32x4*)(Of + ql*68 + d0 + 32) = w1;
    }
    Os1[ql] = ssum[0];
  }
  __syncthreads();

  if (kvh == 0){
    const float rinv = 1.0f / (ssum[0] + Os1[ql]);
    if (mode == 0){
      #pragma unroll
      for (int r=0;r<16;++r){
        int d0 = (r&3) + 8*(r>>2) + 4*l5;
        float f0 = (oo0[r] + Of[ql*68 + d0])      * rinv;
        float f1 = (oo1[r] + Of[ql*68 + d0 + 32]) * rinv;
        ytb[base + (size_t)(d0)*SEQ + q0 + l31]    = f2bf(f0);
        ytb[base + (size_t)(d0+32)*SEQ + q0 + l31] = f2bf(f1);
      }
    } else {
      #pragma unroll
      for (int g=0; g<4; ++g){
        int d0 = 8*g + 4*l5;
        f32x4 w0 = *(const f32x4*)(Of + ql*68 + d0);
        f32x4 w1 = *(const f32x4*)(Of + ql*68 + d0 + 32);
        #pragma unroll
        for (int r=0;r<4;++r){ w0[r] = (w0[r]+oo0[g*4+r])*rinv; w1[r] = (w1[r]+oo1[g*4+r])*rinv; }
        *(f32x4*)(Of + ql*68 + d0)      = w0;
        *(f32x4*)(Of + ql*68 + d0 + 32) = w1;
      }
    }
  }

  if (mode == 1){
    __syncthreads();
    const int b = bh >> 4, h = bh & 15;
    const int qr = tid >> 2, dh = (tid & 3)*16;
    const float* src = Of + qr*68 + dh;
    float* drow = outf + ((size_t)(b*SEQ + qb*128 + qr))*DIM + h*HDIM + dh;
    #pragma unroll
    for (int k2=0;k2<4;++k2)
      *(float4*)(drow + k2*4) = *(const float4*)(src + k2*4);
  }
}

extern "C" void kernel_launch(void* const* d_in, const int* in_sizes, int n_in,
                              void* d_out, int out_size, void* d_ws, size_t ws_size,
                              hipStream_t stream) {
  const float* x   = (const float*)d_in[0];
  const float* x2  = (const float*)d_in[1];
  const float* Wq  = (const float*)d_in[2];
  const float* Wa  = (const float*)d_in[3];
  const float* Wkv = (const float*)d_in[4];
  float* out = (float*)d_out;

  unsigned short* ws = (unsigned short*)d_ws;
  unsigned short* xb   = ws;                      // 4096*1024
  unsigned short* x2b  = xb   + 4096*1024;
  unsigned short* Wqb  = x2b  + 4096*1024;        // 1024*1024
  unsigned short* Wab  = Wqb  + 1024*1024;
  unsigned short* Wkvb = Wab  + 1024*1024;        // 2048*1024
  unsigned short* Qw   = Wkvb + 2048*1024;        // BHND = 4194304 each
  unsigned short* Aw   = Qw   + 4194304;
  unsigned short* Kw   = Aw   + 4194304;
  unsigned short* Vwt  = Kw   + 4194304;          // V^T [bh][d][n] (direct from gemm)
  unsigned short* Ywt  = xb;                      // Y^T [bh][d][n] (xb dead after gemms)

  cast_kernel<<<dim3(4096), dim3(256), 0, stream>>>(x,   xb,   4096*1024/4);
  cast_kernel<<<dim3(4096), dim3(256), 0, stream>>>(x2,  x2b,  4096*1024/4);
  cast_kernel<<<dim3(1024), dim3(256), 0, stream>>>(Wq,  Wqb,  1024*1024/4);
  cast_kernel<<<dim3(1024), dim3(256), 0, stream>>>(Wa,  Wab,  1024*1024/4);
  cast_kernel<<<dim3(2048), dim3(256), 0, stream>>>(Wkv, Wkvb, 2048*1024/4);

  gemm_proj<<<dim3(8, 32),  dim3(256), 0, stream>>>(xb,  Wqb,  Qw, nullptr, 0, 1.0f);
  // A pre-scaled by 0.125*log2(e): query of pass 1 AND key of pass 2
  gemm_proj<<<dim3(8, 32),  dim3(256), 0, stream>>>(x2b, Wab,  Aw, nullptr, 0, SCLOG2);
  gemm_proj<<<dim3(16, 32), dim3(256), 0, stream>>>(xb,  Wkvb, Kw, Vwt,     1, 1.0f);

  // pass 1: Y^T = (softmax(A k^T s) v)^T  -- written directly transposed
  attn_pass<<<dim3(512), dim3(512), 0, stream>>>(Aw, Kw, Vwt, Ywt, nullptr, 0);

  // pass 2: out = softmax(q A^T s) Y
  attn_pass<<<dim3(512), dim3(512), 0, stream>>>(Qw, Aw, Ywt, nullptr, out, 1);
}

// Round 8
// 174.617 us; speedup vs baseline: 1.3838x; 1.1530x over previous
//
#include <hip/hip_runtime.h>

#define DIM 1024
#define HEADS 16
#define HDIM 64
#define SEQ 2048
// 0.125 * log2(e) — folded into A's projection epilogue
#define SCLOG2 0.18033688011112042f

typedef __attribute__((ext_vector_type(8))) short short8;
typedef __attribute__((ext_vector_type(4))) float f32x4;
typedef __attribute__((ext_vector_type(16))) float f32x16;
typedef __attribute__((ext_vector_type(4))) int i32x4;

static __device__ __forceinline__ unsigned short f2bf(float f){
  union { float f; unsigned int u; } v; v.f = f;
  unsigned int r = v.u + 0x7fffu + ((v.u >> 16) & 1u);
  return (unsigned short)(r >> 16);
}

static __device__ __forceinline__ int cvtpk(float lo, float hi){
  int r;
  asm("v_cvt_pk_bf16_f32 %0, %1, %2" : "=v"(r) : "v"(lo), "v"(hi));
  return r;
}
static __device__ __forceinline__ void swap32(int& a, int& b){
  asm("v_permlane32_swap_b32 %0, %1" : "+v"(a), "+v"(b));
}

__device__ __forceinline__ void gl_lds16(const unsigned short* g, unsigned short* l){
  __builtin_amdgcn_global_load_lds((const __attribute__((address_space(1))) void*)g,
                                   (__attribute__((address_space(3))) void*)l, 16, 0, 0);
}

// ---------------- fused cast: all 5 inputs -> contiguous bf16 ws ----------------
// f4-unit boundaries: x 1048576 | x2 2097152 | Wq 2359296 | Wa 2621440 | Wkv 3145728
#define CAST_TOTAL 3145728

__global__ __launch_bounds__(256)
void cast_all(const float* __restrict__ x, const float* __restrict__ x2,
              const float* __restrict__ wq, const float* __restrict__ wa,
              const float* __restrict__ wkv, unsigned short* __restrict__ out)
{
  for (int i = blockIdx.x*256 + threadIdx.x; i < CAST_TOTAL; i += gridDim.x*256){
    const float* src; int off;
    if      (i < 1048576){ src = x;   off = i; }
    else if (i < 2097152){ src = x2;  off = i - 1048576; }
    else if (i < 2359296){ src = wq;  off = i - 2097152; }
    else if (i < 2621440){ src = wa;  off = i - 2359296; }
    else                 { src = wkv; off = i - 2621440; }
    float4 v = ((const float4*)src)[off];
    ushort4 o;
    o.x = f2bf(v.x); o.y = f2bf(v.y); o.z = f2bf(v.z); o.w = f2bf(v.w);
    ((ushort4*)out)[i] = o;
  }
}

// ---------------- merged GEMM: all three projections in one dispatch ----------------
// blocks 0..767:   x  @ [Wq|Wkv]^T  (N=3072): cols 0-1023 -> Q, 1024-2047 -> K, 2048-3071 -> V^T
// blocks 768..1023: x2 @ Wa^T       (N=1024): -> A (scaled by SCLOG2)
// m97-style: global_load_lds staging, linear LDS [128][64], 2 barriers/k-tile
#define GK 1024

__global__ __launch_bounds__(256)
void gemm_all(const unsigned short* __restrict__ xb,  const unsigned short* __restrict__ x2b,
              const unsigned short* __restrict__ Wqb, const unsigned short* __restrict__ Wab,
              const unsigned short* __restrict__ Wkvb,
              unsigned short* __restrict__ Qw, unsigned short* __restrict__ Aw,
              unsigned short* __restrict__ Kw, unsigned short* __restrict__ Vwt)
{
  __shared__ unsigned short Ald[128*64];
  __shared__ unsigned short Bld[128*64];
  const int tid  = threadIdx.x;
  const int lane = tid & 63;
  const int wid  = tid >> 6;
  const int l15 = lane & 15, l4 = lane >> 4;
  const int wm = wid >> 1, wn = wid & 1;

  const int bid = blockIdx.x;
  const unsigned short *Abuf, *Bbuf;
  int mbase, nbase, isA;
  if (bid < 768){
    int nb = bid % 24, mb = bid / 24;
    nbase = nb*128; mbase = mb*128; isA = 0;
    Abuf = xb;
    Bbuf = (nbase < 1024) ? (Wqb + (size_t)nbase*GK) : (Wkvb + (size_t)(nbase-1024)*GK);
  } else {
    int b2 = bid - 768;
    int nb = b2 & 7, mb = b2 >> 3;
    nbase = nb*128; mbase = mb*128; isA = 1;
    Abuf = x2b;
    Bbuf = Wab + (size_t)nbase*GK;
  }

  // staging addresses: wave w round i stages rows w*32+i*8 .. +8 (1KB each)
  const int srow = wid*32 + (lane >> 3);     // + i*8
  const int scol = (lane & 7)*8;
  const unsigned short* gA = Abuf + (size_t)(mbase + srow)*GK + scol;
  const unsigned short* gB = Bbuf + (size_t)srow*GK + scol;
  unsigned short* lA = Ald + (wid*32)*64;    // + i*8*64 ; HW adds lane*16B
  unsigned short* lB = Bld + (wid*32)*64;

  f32x4 acc[4][4];
  #pragma unroll
  for (int i=0;i<4;i++)
    #pragma unroll
    for(int j=0;j<4;j++) acc[i][j] = (f32x4){0.f,0.f,0.f,0.f};

  for (int kt = 0; kt < GK; kt += 64){
    __syncthreads();
    #pragma unroll
    for (int i=0;i<4;++i){
      gl_lds16(gA + (size_t)(i*8)*GK + kt, lA + i*8*64);
      gl_lds16(gB + (size_t)(i*8)*GK + kt, lB + i*8*64);
    }
    __syncthreads();
    #pragma unroll
    for (int kc = 0; kc < 2; ++kc){
      short8 af[4], bf[4];
      #pragma unroll
      for (int mt=0; mt<4; ++mt)
        af[mt] = *(const short8*)(Ald + (wm*64 + mt*16 + l15)*64 + kc*32 + l4*8);
      #pragma unroll
      for (int nt=0; nt<4; ++nt)
        bf[nt] = *(const short8*)(Bld + (wn*64 + nt*16 + l15)*64 + kc*32 + l4*8);
      #pragma unroll
      for (int mt=0; mt<4; ++mt)
        #pragma unroll
        for (int nt=0; nt<4; ++nt)
          acc[mt][nt] = __builtin_amdgcn_mfma_f32_16x16x32_bf16(af[mt], bf[nt], acc[mt][nt], 0,0,0);
    }
  }

  const float scale = isA ? SCLOG2 : 1.0f;
  #pragma unroll
  for (int mt=0; mt<4; ++mt){
    int mrow = mbase + wm*64 + mt*16 + l4*4;   // multiple of 4
    int b = mrow >> 11, nblk = mrow & 2047;
    #pragma unroll
    for (int nt=0; nt<4; ++nt){
      int col = nbase + wn*64 + nt*16 + l15;
      if (isA){
        int h = col >> 6, d = col & 63;
        #pragma unroll
        for (int r=0; r<4; ++r)
          Aw[((size_t)((b*HEADS + h)*SEQ + nblk + r))*HDIM + d] = f2bf(acc[mt][nt][r] * scale);
      } else if (col < 1024){
        int h = col >> 6, d = col & 63;
        #pragma unroll
        for (int r=0; r<4; ++r)
          Qw[((size_t)((b*HEADS + h)*SEQ + nblk + r))*HDIM + d] = f2bf(acc[mt][nt][r]);
      } else if (col < 2048){
        int c2 = col - 1024, h = c2 >> 6, d = c2 & 63;
        #pragma unroll
        for (int r=0; r<4; ++r)
          Kw[((size_t)((b*HEADS + h)*SEQ + nblk + r))*HDIM + d] = f2bf(acc[mt][nt][r]);
      } else {
        int c2 = col - 2048, h = c2 >> 6, d = c2 & 63;
        ushort4 pk;
        pk.x = f2bf(acc[mt][nt][0]);
        pk.y = f2bf(acc[mt][nt][1]);
        pk.z = f2bf(acc[mt][nt][2]);
        pk.w = f2bf(acc[mt][nt][3]);
        *(ushort4*)(Vwt + ((size_t)((b*HEADS + h)*HDIM + d))*SEQ + nblk) = pk;
      }
    }
  }
}

// ---------------- fused flash attention, swapped-operand 32x32, in-block KV split ----------
// Q row-major [bh][q][d]; K row-major [bh][key][d]; V pre-transposed [bh][d][key]
// 8 waves: qw = wid&3 (32 q-rows each), kvh = wid>>2 (keys kvh*1024 .. +1024)
// mode 0: writes Y^T [bh][d][q] bf16. mode 1: writes fp32 out[b][q][h*64+d].
#define KT2 64
#define NTH 16     // tiles per kv half

__global__ __launch_bounds__(512)
void attn_pass(const unsigned short* __restrict__ Qb,
               const unsigned short* __restrict__ Kb,
               const unsigned short* __restrict__ Vtb,
               unsigned short* __restrict__ ytb,
               float* __restrict__ outf,
               int mode)
{
  // staging: [kvh][buf][16 frags * 512 shorts] = 64 KB; merge Of[128][68] f32 + Os overlay
  __shared__ __align__(16) char SHRAW[65536];
  unsigned short* SH = (unsigned short*)SHRAW;
  const int tid = threadIdx.x, lane = tid & 63, wid = tid >> 6;  // 8 waves
  const int l31 = lane & 31, l5 = lane >> 5;
  const int qw = wid & 3, kvh = wid >> 2;

  // XCD-aware decode: 4 bh per XCD, all 16 q-blocks of a bh on one XCD
  const int bid = blockIdx.x;
  const int cx = bid & 7, j = bid >> 3;
  const int bh = cx*4 + (j >> 4);
  const int qb = j & 15;
  const int q0 = qb*128 + qw*32;               // this wave's 32 q-rows
  const size_t base = (size_t)bh * SEQ * HDIM;

  // Q^T B-fragments (col q = l31, k-rows d = db*16 + l5*8 ..+8)
  short8 qf[4];
  #pragma unroll
  for (int db=0; db<4; ++db)
    qf[db] = *(const short8*)(Qb + base + (size_t)(q0 + l31)*HDIM + db*16 + l5*8);

  // staging duty within kv-group: qw 0,1 -> K frags, qw 2,3 -> V frags
  const unsigned short* gsrc[4];
  int ldst[4];
  int sstep;
  const int grpoff = kvh * 16384;
  if (qw < 2){
    #pragma unroll
    for (int f=0; f<4; ++f){
      gsrc[f] = Kb + base + (size_t)(kvh*1024 + qw*32 + l31)*HDIM + f*16 + l5*8;
      ldst[f] = grpoff + (qw*4 + f)*512;
    }
    sstep = KT2*HDIM;
  } else {
    const int db2 = qw - 2;
    #pragma unroll
    for (int f=0; f<4; ++f){
      gsrc[f] = Vtb + base + (size_t)(db2*32 + l31)*SEQ + kvh*1024 + f*16 + l5*8;
      ldst[f] = grpoff + 4096 + (db2*4 + f)*512;
    }
    sstep = KT2;
  }

  f32x16 oo0, oo1, ssum;
  #pragma unroll
  for (int r=0;r<16;++r){ oo0[r]=0.f; oo1[r]=0.f; ssum[r]=0.f; }
  short8 ones;
  #pragma unroll
  for (int jj=0;jj<8;++jj) ones[jj] = (short)0x3F80;

  #pragma unroll
  for (int f=0; f<4; ++f)
    gl_lds16(gsrc[f], SH + ldst[f]);
  __syncthreads();

  for (int t = 0; t < NTH; ++t){
    const int cur = t & 1;
    if (t+1 < NTH){
      const int pbuf = ((t+1) & 1) * 8192;
      #pragma unroll
      for (int f=0; f<4; ++f)
        gl_lds16(gsrc[f] + (size_t)(t+1)*sstep, SH + ldst[f] + pbuf);
    }
    const unsigned short* Kc = SH + grpoff + cur*8192;
    const unsigned short* Vc = Kc + 4096;

    // S^T = K * Q^T : lane = col q0+l31, rows key = kb*32 + (r&3)+8*(r>>2)+4*l5
    float p[32];
    #pragma unroll
    for (int kb=0; kb<2; ++kb){
      f32x16 sacc;
      #pragma unroll
      for (int r=0;r<16;++r) sacc[r]=0.f;
      #pragma unroll
      for (int db=0; db<4; ++db){
        short8 kfr = *(const short8*)(Kc + (kb*4+db)*512 + lane*8);
        sacc = __builtin_amdgcn_mfma_f32_32x32x16_bf16(kfr, qf[db], sacc, 0,0,0);
      }
      #pragma unroll
      for (int r=0;r<16;++r)
        p[kb*16+r] = exp2f(sacc[r]);     // scale pre-folded into A projection
    }

    // build P^T B-frags in registers; PV + ones-MFMA rowsum
    #pragma unroll
    for (int kb2=0; kb2<4; ++kb2){
      const int pb = (kb2>>1)*16 + (kb2&1)*8;
      int a0 = cvtpk(p[pb+0], p[pb+1]);
      int b0 = cvtpk(p[pb+4], p[pb+5]);
      int a1 = cvtpk(p[pb+2], p[pb+3]);
      int b1 = cvtpk(p[pb+6], p[pb+7]);
      swap32(a0, b0);
      swap32(a1, b1);
      i32x4 pav; pav[0]=a0; pav[1]=a1; pav[2]=b0; pav[3]=b1;
      short8 paf = *(short8*)&pav;
      ssum = __builtin_amdgcn_mfma_f32_32x32x16_bf16(ones, paf, ssum, 0,0,0);
      short8 v0 = *(const short8*)(Vc + (0*4+kb2)*512 + lane*8);
      oo0 = __builtin_amdgcn_mfma_f32_32x32x16_bf16(v0, paf, oo0, 0,0,0);
      short8 v1 = *(const short8*)(Vc + (1*4+kb2)*512 + lane*8);
      oo1 = __builtin_amdgcn_mfma_f32_32x32x16_bf16(v1, paf, oo1, 0,0,0);
    }
    __syncthreads();
  }

  // ---- in-block merge of the two kv halves ----
  float* Of  = (float*)SHRAW;                 // [128][68]
  float* Os1 = (float*)(SHRAW + 128*68*4);    // [128]
  const int ql = qw*32 + l31;

  if (kvh == 1){
    #pragma unroll
    for (int g=0; g<4; ++g){
      f32x4 w0, w1;
      #pragma unroll
      for (int r=0;r<4;++r){ w0[r] = oo0[g*4+r]; w1[r] = oo1[g*4+r]; }
      int d0 = 8*g + 4*l5;
      *(f32x4*)(Of + ql*68 + d0)      = w0;
      *(f32x4*)(Of + ql*68 + d0 + 32) = w1;
    }
    Os1[ql] = ssum[0];
  }
  __syncthreads();

  if (kvh == 0){
    const float rinv = 1.0f / (ssum[0] + Os1[ql]);
    if (mode == 0){
      #pragma unroll
      for (int r=0;r<16;++r){
        int d0 = (r&3) + 8*(r>>2) + 4*l5;
        float f0 = (oo0[r] + Of[ql*68 + d0])      * rinv;
        float f1 = (oo1[r] + Of[ql*68 + d0 + 32]) * rinv;
        ytb[base + (size_t)(d0)*SEQ + q0 + l31]    = f2bf(f0);
        ytb[base + (size_t)(d0+32)*SEQ + q0 + l31] = f2bf(f1);
      }
    } else {
      #pragma unroll
      for (int g=0; g<4; ++g){
        int d0 = 8*g + 4*l5;
        f32x4 w0 = *(const f32x4*)(Of + ql*68 + d0);
        f32x4 w1 = *(const f32x4*)(Of + ql*68 + d0 + 32);
        #pragma unroll
        for (int r=0;r<4;++r){ w0[r] = (w0[r]+oo0[g*4+r])*rinv; w1[r] = (w1[r]+oo1[g*4+r])*rinv; }
        *(f32x4*)(Of + ql*68 + d0)      = w0;
        *(f32x4*)(Of + ql*68 + d0 + 32) = w1;
      }
    }
  }

  if (mode == 1){
    __syncthreads();
    const int b = bh >> 4, h = bh & 15;
    const int qr = tid >> 2, dh = (tid & 3)*16;
    const float* src = Of + qr*68 + dh;
    float* drow = outf + ((size_t)(b*SEQ + qb*128 + qr))*DIM + h*HDIM + dh;
    #pragma unroll
    for (int k2=0;k2<4;++k2)
      *(float4*)(drow + k2*4) = *(const float4*)(src + k2*4);
  }
}

extern "C" void kernel_launch(void* const* d_in, const int* in_sizes, int n_in,
                              void* d_out, int out_size, void* d_ws, size_t ws_size,
                              hipStream_t stream) {
  const float* x   = (const float*)d_in[0];
  const float* x2  = (const float*)d_in[1];
  const float* Wq  = (const float*)d_in[2];
  const float* Wa  = (const float*)d_in[3];
  const float* Wkv = (const float*)d_in[4];
  float* out = (float*)d_out;

  unsigned short* ws = (unsigned short*)d_ws;
  unsigned short* xb   = ws;                      // 4096*1024
  unsigned short* x2b  = xb   + 4096*1024;
  unsigned short* Wqb  = x2b  + 4096*1024;        // 1024*1024
  unsigned short* Wab  = Wqb  + 1024*1024;
  unsigned short* Wkvb = Wab  + 1024*1024;        // 2048*1024
  unsigned short* Qw   = Wkvb + 2048*1024;        // BHND = 4194304 each
  unsigned short* Aw   = Qw   + 4194304;
  unsigned short* Kw   = Aw   + 4194304;
  unsigned short* Vwt  = Kw   + 4194304;          // V^T [bh][d][n] (direct from gemm)
  unsigned short* Ywt  = xb;                      // Y^T [bh][d][n] (xb dead after gemm)

  // one fused cast (ws front region is exactly [xb|x2b|Wqb|Wab|Wkvb])
  cast_all<<<dim3(3072), dim3(256), 0, stream>>>(x, x2, Wq, Wa, Wkv, ws);

  // one merged GEMM: Q, K, V^T, A(scaled)
  gemm_all<<<dim3(1024), dim3(256), 0, stream>>>(xb, x2b, Wqb, Wab, Wkvb, Qw, Aw, Kw, Vwt);

  // pass 1: Y^T = (softmax(A k^T s) v)^T  -- written directly transposed
  attn_pass<<<dim3(512), dim3(512), 0, stream>>>(Aw, Kw, Vwt, Ywt, nullptr, 0);

  // pass 2: out = softmax(q A^T s) Y
  attn_pass<<<dim3(512), dim3(512), 0, stream>>>(Qw, Aw, Ywt, nullptr, out, 1);
}